// Round 7
// baseline (1416.102 us; speedup 1.0000x reference)
//
#include <hip/hip_runtime.h>
#include <cstdint>
#include <cstddef>

#define B   32
#define N   4096
#define NP  512
#define NS  16
#define C   256
#define CIN 259
#define HID 128
#define SB  (NP*NS)      // 8192 columns per batch
#define S   (B*SB)       // 262144 total columns
#define EPSF 1e-5f

#define FPS_BLOCKS 32
#define TR_BLOCKS  (B*256)   // 8192 transpose tiles
#define PREP_BLOCKS 64

typedef __attribute__((ext_vector_type(8))) short short8;
typedef __attribute__((ext_vector_type(4))) float floatx4;

__device__ __forceinline__ float bf2f(unsigned short u) {
    return __uint_as_float(((unsigned)u) << 16);
}
__device__ __forceinline__ unsigned short f2bf(float f) {
    unsigned u = __float_as_uint(f);
    return (unsigned short)((u + 0x7FFFu + ((u >> 16) & 1u)) >> 16);
}

// wave64 max of nonneg-float bits via DPP (VALU pipe, no LDS crossbar), result uniform
__device__ __forceinline__ int wave_max_i32(int x) {
    int y;
    y = __builtin_amdgcn_update_dpp(0, x, 0x111, 0xf, 0xf, true); x = (y > x) ? y : x;
    y = __builtin_amdgcn_update_dpp(0, x, 0x112, 0xf, 0xf, true); x = (y > x) ? y : x;
    y = __builtin_amdgcn_update_dpp(0, x, 0x114, 0xf, 0xf, true); x = (y > x) ? y : x;
    y = __builtin_amdgcn_update_dpp(0, x, 0x118, 0xf, 0xf, true); x = (y > x) ? y : x;
    y = __builtin_amdgcn_update_dpp(0, x, 0x142, 0xa, 0xf, true); x = (y > x) ? y : x;
    y = __builtin_amdgcn_update_dpp(0, x, 0x143, 0xc, 0xf, true); x = (y > x) ? y : x;
    return __builtin_amdgcn_readlane(x, 63);
}
__device__ __forceinline__ unsigned wave_max_u32(unsigned x) {
    unsigned y;
    y = (unsigned)__builtin_amdgcn_update_dpp(0, (int)x, 0x111, 0xf, 0xf, true); x = (y > x) ? y : x;
    y = (unsigned)__builtin_amdgcn_update_dpp(0, (int)x, 0x112, 0xf, 0xf, true); x = (y > x) ? y : x;
    y = (unsigned)__builtin_amdgcn_update_dpp(0, (int)x, 0x114, 0xf, 0xf, true); x = (y > x) ? y : x;
    y = (unsigned)__builtin_amdgcn_update_dpp(0, (int)x, 0x118, 0xf, 0xf, true); x = (y > x) ? y : x;
    y = (unsigned)__builtin_amdgcn_update_dpp(0, (int)x, 0x142, 0xa, 0xf, true); x = (y > x) ? y : x;
    y = (unsigned)__builtin_amdgcn_update_dpp(0, (int)x, 0x143, 0xc, 0xf, true); x = (y > x) ? y : x;
    return (unsigned)__builtin_amdgcn_readlane((int)x, 63);
}

// ---------------- fused front: FPS + ball query + feat transpose(bf16) + weight prep ----------------
__global__ __launch_bounds__(512) void fused_front_kernel(
        const float* __restrict__ seed, const float* __restrict__ xyz,
        const float* __restrict__ feat, const float* __restrict__ w1,
        const float* __restrict__ w2, const float* __restrict__ w3,
        unsigned short* __restrict__ featT, unsigned short* __restrict__ w1fb,
        unsigned short* __restrict__ w2b, unsigned short* __restrict__ w3b,
        float* __restrict__ stats, int* __restrict__ idx,
        float* __restrict__ out_newxyz, float* __restrict__ out_inds_f) {
    __shared__ float smem[3 * N];                 // 48 KB overlay
    __shared__ unsigned long long slot8[16];      // [parity][wave]
    __shared__ int sbinds[NP];
    int bid = blockIdx.x;
    int t = threadIdx.x;

    if (bid >= FPS_BLOCKS) {
        int hb = bid - FPS_BLOCKS;
        if (hb < TR_BLOCKS) {
            // ---- transpose feat (B,C,N) fp32 -> featT (B,N,256) bf16, 32x128 tile ----
            float* ls = smem;
            int b2 = hb >> 8, rem = hb & 255;
            int ct = rem >> 5, jt = rem & 31;
            int c0 = ct * 32, j0 = jt * 128;
            const float* src = feat + (size_t)b2 * C * N;
            #pragma unroll
            for (int i = 0; i < 8; i++) {
                int lin = t + 512 * i;
                int jj = lin & 127, cc = lin >> 7;
                ls[cc * 129 + jj] = src[(size_t)(c0 + cc) * N + j0 + jj];
            }
            __syncthreads();
            int c8 = t & 3, jj = t >> 2;
            unsigned pk[4];
            #pragma unroll
            for (int q = 0; q < 4; q++) {
                float f0 = ls[(c8 * 8 + 2 * q) * 129 + jj];
                float f1 = ls[(c8 * 8 + 2 * q + 1) * 129 + jj];
                pk[q] = (unsigned)f2bf(f0) | ((unsigned)f2bf(f1) << 16);
            }
            *(uint4*)&featT[((size_t)b2 * N + j0 + jj) * 256 + c0 + c8 * 8] =
                make_uint4(pk[0], pk[1], pk[2], pk[3]);
        } else {
            // ---- prep: weights -> bf16 [o][k]; zero stats ----
            int i0 = (hb - TR_BLOCKS) * 512 + t;
            if (i0 < 256 * HID) { int o = i0 >> 8, k = i0 & 255; w1fb[i0] = f2bf(w1[o * CIN + 3 + k]); }
            if (i0 < HID * HID) { w2b[i0] = f2bf(w2[i0]); w3b[i0] = f2bf(w3[i0]); }
            if (i0 < 3 * 512) stats[i0] = 0.f;
        }
        return;
    }

    // ---- FPS for batch b = bid ----
    float* sx = smem;
    float* sy = smem + N;
    float* sz = smem + 2 * N;
    int b = bid;
    const float* sp = seed + (size_t)b * N * 3;
    float px[8], py[8], pz[8], dloc[8];
    #pragma unroll
    for (int u = 0; u < 8; u++) {
        int i = t + 512 * u;
        float x = sp[i * 3 + 0], y = sp[i * 3 + 1], z = sp[i * 3 + 2];
        sx[i] = x; sy[i] = y; sz[i] = z;
        px[u] = x; py[u] = y; pz[u] = z;
        dloc[u] = 1e10f;
    }
    if (t == 0) sbinds[0] = 0;
    if (t < 16) slot8[t] = 0ull;
    __syncthreads();
    int last = 0;
    int lane = t & 63, w = t >> 6;
    for (int k = 1; k < NP; k++) {
        float lx = sx[last], ly = sy[last], lz = sz[last];
        float bv = -1.f; int bi = 0x7fffffff;
        #pragma unroll
        for (int u = 0; u < 8; u++) {
            int i = t + 512 * u;
            float dx = __fsub_rn(px[u], lx);
            float dy = __fsub_rn(py[u], ly);
            float dz = __fsub_rn(pz[u], lz);
            float d  = __fadd_rn(__fadd_rn(__fmul_rn(dx, dx), __fmul_rn(dy, dy)), __fmul_rn(dz, dz));
            float dm = fminf(dloc[u], d);
            dloc[u] = dm;
            if (dm > bv || (dm == bv && i < bi)) { bv = dm; bi = i; }
        }
        int wm = wave_max_i32(__float_as_int(bv));
        unsigned cand = (__float_as_int(bv) == wm) ? ~(unsigned)bi : 0u;
        unsigned win = wave_max_u32(cand);
        int wbi = (int)(~win);
        if (lane == 0)
            slot8[(k & 1) * 8 + w] =
                (((unsigned long long)(unsigned)wm) << 12) | (unsigned)(4095 - wbi);
        __syncthreads();
        unsigned long long best = slot8[(k & 1) * 8];
        #pragma unroll
        for (int j = 1; j < 8; j++) {
            unsigned long long v = slot8[(k & 1) * 8 + j];
            if (v > best) best = v;
        }
        last = 4095 - (int)(best & 0xFFFull);
        if (t == 0) sbinds[k] = last;
    }
    __syncthreads();
    {
        int p = t;   // 512 threads cover NP=512
        int j = sbinds[p];
        const float* xb = xyz + ((size_t)b * N + j) * 3;
        float* ob = out_newxyz + ((size_t)b * NP + p) * 3;
        ob[0] = xb[0]; ob[1] = xb[1]; ob[2] = xb[2];
        out_inds_f[b * NP + p] = (float)j;
    }
    // ---- ball query for this batch: reload smem with xyz, 8 waves x 64 queries ----
    __syncthreads();
    {
        const float* xb = xyz + (size_t)b * N * 3;
        #pragma unroll
        for (int u = 0; u < 8; u++) {
            int i = t + 512 * u;
            sx[i] = xb[i * 3]; sy[i] = xb[i * 3 + 1]; sz[i] = xb[i * 3 + 2];
        }
    }
    __syncthreads();
    for (int qq = 0; qq < 64; qq++) {
        int q = w * 64 + qq;
        int jq = sbinds[q];
        float qx = sx[jq], qy = sy[jq], qz = sz[jq];
        int* out = idx + ((size_t)(b * NP + q)) * NS;
        int cnt = 0, first = -1;
        for (int it = 0; it < 64; it++) {
            int j = it * 64 + lane;
            float dx = __fsub_rn(sx[j], qx);
            float dy = __fsub_rn(sy[j], qy);
            float dz = __fsub_rn(sz[j], qz);
            float d2 = __fadd_rn(__fadd_rn(__fmul_rn(dx, dx), __fmul_rn(dy, dy)), __fmul_rn(dz, dz));
            bool inb = d2 < 0.09f;
            unsigned long long m = __ballot(inb);
            if (m) {
                if (first < 0) first = it * 64 + __builtin_ctzll(m);
                if (inb) {
                    int r = cnt + __popcll(m & ((1ull << lane) - 1ull));
                    if (r < NS) out[r] = j;
                }
                cnt += __popcll(m);
                if (cnt >= NS) break;
            }
        }
        if (cnt < NS && lane >= cnt && lane < NS) out[lane] = first;
    }
}

// ---------------- GEMM1 (MFMA bf16): y1[s][o] = w1feat . gathered featT + xyz epilogue, + stats ----------------
__global__ __launch_bounds__(256) void gemm1_mfma(
        const unsigned short* __restrict__ w1fb, const float* __restrict__ w1raw,
        const unsigned short* __restrict__ featT, const float* __restrict__ newxyz,
        const float* __restrict__ xyz, const int* __restrict__ idx,
        unsigned short* __restrict__ y1, float* __restrict__ stOut) {
    __shared__ unsigned short Xs[128][136];       // [s][k] slab, reused as [s][o] out tile
    __shared__ float xn0[128], xn1[128], xn2[128];
    __shared__ int jl[128];
    __shared__ float bsum[128], bsq[128];
    int t = threadIdx.x;
    int s0 = blockIdx.x * 128;
    int b = s0 >> 13;
    if (t < 128) {
        int pn = (s0 & (SB - 1)) + t;
        int p = pn >> 4, n = pn & 15;
        int j = idx[((size_t)(b * NP + p)) * NS + n];
        jl[t] = j;
        const float* xb = xyz + ((size_t)(b * N + j)) * 3;
        const float* nq = newxyz + ((size_t)(b * NP + p)) * 3;
        xn0[t] = (xb[0] - nq[0]) / 0.3f;
        xn1[t] = (xb[1] - nq[1]) / 0.3f;
        xn2[t] = (xb[2] - nq[2]) / 0.3f;
        bsum[t] = 0.f; bsq[t] = 0.f;
    }
    __syncthreads();
    int lane = t & 63, w = t >> 6;
    int row16 = lane & 15, quad = lane >> 4;
    floatx4 acc[2][8];
    #pragma unroll
    for (int mt = 0; mt < 2; mt++)
        #pragma unroll
        for (int nt = 0; nt < 8; nt++)
            acc[mt][nt] = (floatx4){0.f, 0.f, 0.f, 0.f};
    int ss = t >> 1, hh = (t & 1) * 64;
    const unsigned short* grow = featT + ((size_t)b * N + jl[ss]) * 256 + hh;
    for (int slab = 0; slab < 2; slab++) {
        int k0 = slab * 128;
        {
            const uint4* src = (const uint4*)(grow + k0);
            #pragma unroll
            for (int i = 0; i < 8; i++)
                *(uint4*)&Xs[ss][hh + i * 8] = src[i];
        }
        __syncthreads();
        #pragma unroll
        for (int kk = 0; kk < 128; kk += 32) {
            short8 a0 = *(const short8*)&w1fb[(size_t)(w * 32 + row16) * 256 + k0 + kk + quad * 8];
            short8 a1 = *(const short8*)&w1fb[(size_t)(w * 32 + 16 + row16) * 256 + k0 + kk + quad * 8];
            #pragma unroll
            for (int nt = 0; nt < 8; nt++) {
                short8 bf = *(const short8*)&Xs[nt * 16 + row16][kk + quad * 8];
                acc[0][nt] = __builtin_amdgcn_mfma_f32_16x16x32_bf16(a0, bf, acc[0][nt], 0, 0, 0);
                acc[1][nt] = __builtin_amdgcn_mfma_f32_16x16x32_bf16(a1, bf, acc[1][nt], 0, 0, 0);
            }
        }
        __syncthreads();
    }
    // epilogue: + w1_xyz . xn (fp32), accumulate stats, pack bf16 tile [s][o]
    float wa[8], wbv[8], wc[8];
    #pragma unroll
    for (int mt = 0; mt < 2; mt++)
        #pragma unroll
        for (int r = 0; r < 4; r++) {
            int o = w * 32 + mt * 16 + quad * 4 + r;
            const float* wr = w1raw + (size_t)o * CIN;
            wa[mt * 4 + r] = wr[0]; wbv[mt * 4 + r] = wr[1]; wc[mt * 4 + r] = wr[2];
        }
    float x0l[8], x1l[8], x2l[8];
    #pragma unroll
    for (int nt = 0; nt < 8; nt++) {
        int s = nt * 16 + row16;
        x0l[nt] = xn0[s]; x1l[nt] = xn1[s]; x2l[nt] = xn2[s];
    }
    float lsum[8] = {}, lsq[8] = {};
    #pragma unroll
    for (int mt = 0; mt < 2; mt++)
        #pragma unroll
        for (int nt = 0; nt < 8; nt++) {
            int s = nt * 16 + row16;
            int ob = w * 32 + mt * 16 + quad * 4;
            floatx4 a = acc[mt][nt];
            float v0 = a[0] + wa[mt*4+0]*x0l[nt] + wbv[mt*4+0]*x1l[nt] + wc[mt*4+0]*x2l[nt];
            float v1 = a[1] + wa[mt*4+1]*x0l[nt] + wbv[mt*4+1]*x1l[nt] + wc[mt*4+1]*x2l[nt];
            float v2 = a[2] + wa[mt*4+2]*x0l[nt] + wbv[mt*4+2]*x1l[nt] + wc[mt*4+2]*x2l[nt];
            float v3 = a[3] + wa[mt*4+3]*x0l[nt] + wbv[mt*4+3]*x1l[nt] + wc[mt*4+3]*x2l[nt];
            lsum[mt*4+0] += v0; lsq[mt*4+0] = fmaf(v0, v0, lsq[mt*4+0]);
            lsum[mt*4+1] += v1; lsq[mt*4+1] = fmaf(v1, v1, lsq[mt*4+1]);
            lsum[mt*4+2] += v2; lsq[mt*4+2] = fmaf(v2, v2, lsq[mt*4+2]);
            lsum[mt*4+3] += v3; lsq[mt*4+3] = fmaf(v3, v3, lsq[mt*4+3]);
            unsigned p0 = (unsigned)f2bf(v0) | ((unsigned)f2bf(v1) << 16);
            unsigned p1 = (unsigned)f2bf(v2) | ((unsigned)f2bf(v3) << 16);
            *(uint2*)&Xs[s][ob] = make_uint2(p0, p1);
        }
    #pragma unroll
    for (int mt = 0; mt < 2; mt++)
        #pragma unroll
        for (int r = 0; r < 4; r++) {
            int o = w * 32 + mt * 16 + quad * 4 + r;
            atomicAdd(&bsum[o], lsum[mt*4+r]);
            atomicAdd(&bsq[o],  lsq[mt*4+r]);
        }
    __syncthreads();
    int c = t & 15, sr = t >> 4;
    #pragma unroll
    for (int i = 0; i < 8; i++) {
        int s = sr + 16 * i;
        uint4 v = *(const uint4*)&Xs[s][c * 8];
        *(uint4*)&y1[(size_t)(s0 + s) * 128 + c * 8] = v;
    }
    if (t < 128) { atomicAdd(&stOut[t], bsum[t]); atomicAdd(&stOut[128 + t], bsq[t]); }
}

// ---------------- GEMM2/3 (MFMA bf16): bn params inline, X = relu(affine(yprev)), Y = W*X, + stats ----------------
__global__ __launch_bounds__(256) void gemm_bn_mfma(
        const unsigned short* __restrict__ wb16, const unsigned short* __restrict__ yprev,
        const float* __restrict__ stPrev, const float* __restrict__ gp,
        const float* __restrict__ bep, unsigned short* __restrict__ yout,
        float* __restrict__ stOut) {
    __shared__ unsigned short Xs[128][136];
    __shared__ float ssc[128], ssh[128];
    __shared__ float bsum[128], bsq[128];
    int t = threadIdx.x;
    int s0 = blockIdx.x * 128;
    if (t < 128) {
        float mean = stPrev[t] * (1.f / (float)S);
        float var  = stPrev[128 + t] * (1.f / (float)S) - mean * mean;
        float sc = gp[t] / sqrtf(var + EPSF);
        ssc[t] = sc;
        ssh[t] = bep[t] - mean * sc;
        bsum[t] = 0.f; bsq[t] = 0.f;
    }
    __syncthreads();
    int ss = t >> 1, hh = (t & 1) * 64;
    {
        const uint4* src = (const uint4*)&yprev[(size_t)(s0 + ss) * 128 + hh];
        #pragma unroll
        for (int i = 0; i < 8; i++) {
            uint4 raw = src[i];
            int kb = hh + i * 8;
            float4 c0 = *(float4*)&ssc[kb];
            float4 c1 = *(float4*)&ssc[kb + 4];
            float4 h0 = *(float4*)&ssh[kb];
            float4 h1 = *(float4*)&ssh[kb + 4];
            float f0 = fmaxf(0.f, fmaf(bf2f((unsigned short)(raw.x & 0xFFFF)), c0.x, h0.x));
            float f1 = fmaxf(0.f, fmaf(bf2f((unsigned short)(raw.x >> 16)),    c0.y, h0.y));
            float f2 = fmaxf(0.f, fmaf(bf2f((unsigned short)(raw.y & 0xFFFF)), c0.z, h0.z));
            float f3 = fmaxf(0.f, fmaf(bf2f((unsigned short)(raw.y >> 16)),    c0.w, h0.w));
            float f4 = fmaxf(0.f, fmaf(bf2f((unsigned short)(raw.z & 0xFFFF)), c1.x, h1.x));
            float f5 = fmaxf(0.f, fmaf(bf2f((unsigned short)(raw.z >> 16)),    c1.y, h1.y));
            float f6 = fmaxf(0.f, fmaf(bf2f((unsigned short)(raw.w & 0xFFFF)), c1.z, h1.z));
            float f7 = fmaxf(0.f, fmaf(bf2f((unsigned short)(raw.w >> 16)),    c1.w, h1.w));
            unsigned o0 = (unsigned)f2bf(f0) | ((unsigned)f2bf(f1) << 16);
            unsigned o1 = (unsigned)f2bf(f2) | ((unsigned)f2bf(f3) << 16);
            unsigned o2 = (unsigned)f2bf(f4) | ((unsigned)f2bf(f5) << 16);
            unsigned o3 = (unsigned)f2bf(f6) | ((unsigned)f2bf(f7) << 16);
            *(uint4*)&Xs[ss][kb] = make_uint4(o0, o1, o2, o3);
        }
    }
    __syncthreads();
    int lane = t & 63, w = t >> 6;
    int row16 = lane & 15, quad = lane >> 4;
    floatx4 acc[2][8];
    #pragma unroll
    for (int mt = 0; mt < 2; mt++)
        #pragma unroll
        for (int nt = 0; nt < 8; nt++)
            acc[mt][nt] = (floatx4){0.f, 0.f, 0.f, 0.f};
    #pragma unroll
    for (int kk = 0; kk < 128; kk += 32) {
        short8 a0 = *(const short8*)&wb16[(size_t)(w * 32 + row16) * 128 + kk + quad * 8];
        short8 a1 = *(const short8*)&wb16[(size_t)(w * 32 + 16 + row16) * 128 + kk + quad * 8];
        #pragma unroll
        for (int nt = 0; nt < 8; nt++) {
            short8 bf = *(const short8*)&Xs[nt * 16 + row16][kk + quad * 8];
            acc[0][nt] = __builtin_amdgcn_mfma_f32_16x16x32_bf16(a0, bf, acc[0][nt], 0, 0, 0);
            acc[1][nt] = __builtin_amdgcn_mfma_f32_16x16x32_bf16(a1, bf, acc[1][nt], 0, 0, 0);
        }
    }
    __syncthreads();
    float lsum[8] = {}, lsq[8] = {};
    #pragma unroll
    for (int mt = 0; mt < 2; mt++)
        #pragma unroll
        for (int nt = 0; nt < 8; nt++) {
            int s = nt * 16 + row16;
            int ob = w * 32 + mt * 16 + quad * 4;
            floatx4 a = acc[mt][nt];
            lsum[mt*4+0] += a[0]; lsq[mt*4+0] = fmaf(a[0], a[0], lsq[mt*4+0]);
            lsum[mt*4+1] += a[1]; lsq[mt*4+1] = fmaf(a[1], a[1], lsq[mt*4+1]);
            lsum[mt*4+2] += a[2]; lsq[mt*4+2] = fmaf(a[2], a[2], lsq[mt*4+2]);
            lsum[mt*4+3] += a[3]; lsq[mt*4+3] = fmaf(a[3], a[3], lsq[mt*4+3]);
            unsigned p0 = (unsigned)f2bf(a[0]) | ((unsigned)f2bf(a[1]) << 16);
            unsigned p1 = (unsigned)f2bf(a[2]) | ((unsigned)f2bf(a[3]) << 16);
            *(uint2*)&Xs[s][ob] = make_uint2(p0, p1);
        }
    #pragma unroll
    for (int mt = 0; mt < 2; mt++)
        #pragma unroll
        for (int r = 0; r < 4; r++) {
            int o = w * 32 + mt * 16 + quad * 4 + r;
            atomicAdd(&bsum[o], lsum[mt*4+r]);
            atomicAdd(&bsq[o],  lsq[mt*4+r]);
        }
    __syncthreads();
    int c = t & 15, sr = t >> 4;
    #pragma unroll
    for (int i = 0; i < 8; i++) {
        int s = sr + 16 * i;
        uint4 v = *(const uint4*)&Xs[s][c * 8];
        *(uint4*)&yout[(size_t)(s0 + s) * 128 + c * 8] = v;
    }
    if (t < 128) { atomicAdd(&stOut[t], bsum[t]); atomicAdd(&stOut[128 + t], bsq[t]); }
}

// ---------------- final: bn3 inline, affine+relu+max over NS (y3 bf16 [s][o]) ----------------
__global__ __launch_bounds__(256) void maxpool_kernel(const unsigned short* __restrict__ y3,
        const float* __restrict__ st, const float* __restrict__ gp,
        const float* __restrict__ bep, float* __restrict__ out1) {
    int g = blockIdx.x * 256 + threadIdx.x;   // (b, oc, p), p fastest
    int p = g & 511;
    int oc = (g >> 9) & 15;
    int b = g >> 13;
    float sc[8], sh[8];
    #pragma unroll
    for (int j = 0; j < 8; j++) {
        int o = oc * 8 + j;
        float mean = st[o] * (1.f / (float)S);
        float var  = st[128 + o] * (1.f / (float)S) - mean * mean;
        float s = gp[o] / sqrtf(var + EPSF);
        sc[j] = s;
        sh[j] = bep[o] - mean * s;
    }
    float m[8];
    #pragma unroll
    for (int j = 0; j < 8; j++) m[j] = 0.f;   // relu floor
    size_t base = ((size_t)(b * NP + p) * NS) * 128 + oc * 8;
    #pragma unroll
    for (int n = 0; n < 16; n++) {
        uint4 v = *(const uint4*)&y3[base + (size_t)n * 128];
        unsigned ww[4] = {v.x, v.y, v.z, v.w};
        #pragma unroll
        for (int j = 0; j < 4; j++) {
            m[2*j]   = fmaxf(m[2*j],   fmaf(bf2f((unsigned short)(ww[j] & 0xFFFF)), sc[2*j],   sh[2*j]));
            m[2*j+1] = fmaxf(m[2*j+1], fmaf(bf2f((unsigned short)(ww[j] >> 16)),    sc[2*j+1], sh[2*j+1]));
        }
    }
    #pragma unroll
    for (int j = 0; j < 8; j++)
        out1[((size_t)b * HID + oc * 8 + j) * NP + p] = m[j];
}

extern "C" void kernel_launch(void* const* d_in, const int* in_sizes, int n_in,
                              void* d_out, int out_size, void* d_ws, size_t ws_size,
                              hipStream_t stream) {
    const float* xyz  = (const float*)d_in[0];
    const float* feat = (const float*)d_in[1];
    const float* seed = (const float*)d_in[2];
    const float* w1 = (const float*)d_in[3];
    const float* g1 = (const float*)d_in[4];
    const float* be1 = (const float*)d_in[5];
    const float* w2 = (const float*)d_in[6];
    const float* g2 = (const float*)d_in[7];
    const float* be2 = (const float*)d_in[8];
    const float* w3 = (const float*)d_in[9];
    const float* g3 = (const float*)d_in[10];
    const float* be3 = (const float*)d_in[11];

    float* out_newxyz = (float*)d_out;                 // (B,NP,3)
    float* out_feat   = out_newxyz + B * NP * 3;       // (B,HID,NP)
    float* out_inds   = out_feat + B * HID * NP;       // (B,NP) as float

    float* stats = (float*)d_ws;                       // 3 layers x [sum|sq] x 128 (512-stride)
    int*   idx   = (int*)(stats + 3 * 512);            // B*NP*NS
    unsigned short* w1fb  = (unsigned short*)(idx + (size_t)B * NP * NS);
    unsigned short* w2b   = w1fb + 256 * HID;
    unsigned short* w3b   = w2b + HID * HID;
    unsigned short* featT = w3b + HID * HID;           // B*N*256 bf16
    unsigned short* y1    = featT + (size_t)B * N * 256;   // S*128 bf16
    unsigned short* y2    = featT;                     // alias: featT dead after gemm1 (same size)
    unsigned short* y3    = y1;                        // alias: y1 dead after gemm2

    size_t need = (size_t)(3 * 512) * 4 + (size_t)B * NP * NS * 4
                + (size_t)(256 * HID + 2 * HID * HID) * 2
                + 2ull * (size_t)B * N * 256 * 2;
    if (ws_size < need) return;

    fused_front_kernel<<<FPS_BLOCKS + TR_BLOCKS + PREP_BLOCKS, 512, 0, stream>>>(
        seed, xyz, feat, w1, w2, w3, featT, w1fb, w2b, w3b, stats,
        idx, out_newxyz, out_inds);
    gemm1_mfma<<<S / 128, 256, 0, stream>>>(w1fb, w1, featT, out_newxyz, xyz, idx, y1, stats);
    gemm_bn_mfma<<<S / 128, 256, 0, stream>>>(w2b, y1, stats, g1, be1, y2, stats + 512);
    gemm_bn_mfma<<<S / 128, 256, 0, stream>>>(w3b, y2, stats + 512, g2, be2, y3, stats + 1024);
    maxpool_kernel<<<(B * 16 * NP) / 256, 256, 0, stream>>>(y3, stats + 1024, g3, be3, out_feat);
}